// Round 5
// baseline (598.912 us; speedup 1.0000x reference)
//
#include <hip/hip_runtime.h>
#include <math.h>

// ---------------------------------------------------------------------------
// Problem: N=8192 tokens, D=4096, E=8 experts, R=16, top_k=2. ALL fp32 in/out.
// out = x @ W^T + sum_{e in top2} 2*w_e * (x @ A[e]^T) @ B[e]^T
// Strategy: convert x,W,A,B to bf16 in ws; fold LoRA down-proj into the base
// GEMM as a K-extension (K = 4096 + 128), fp32 accumulate, fp32 out.
// k_main: 256x256 tile, BK=64 double-buffered, 8-phase counted-vmcnt schedule.
// Round-5 = round-4 resubmission (round-4 bench was an infra failure with no
// kernel evidence; audit found no hang/deadlock/resource violation):
//   16 waves (1024 thr), wave-tile 64x64 -> acc 64 VGPR/thread, total ~124
//   regs <= 128 -> 4 waves/SIMD (was 2 at 240 regs). Theory: phase drain/LDS
//   time was serialized with MFMA because only 2 barrier-locked waves shared
//   each SIMD; doubling resident waves feeds the MFMA pipe during drains.
//   MfmaUtil 43% -> predicted ~60%.
// LDS tiles use an XOR-8 swizzle (chunk ^= row&7) applied in GLOBAL address
// space during staging (global_load_lds LDS write pattern is fixed).
// ---------------------------------------------------------------------------

#define NTOK 8192
#define DIM  4096
#define NEXP 8
#define RANK 16
#define KAUG (NEXP * RANK)   // 128
#define KSPLIT 4             // k_ax split-K factor
#define NKT  ((DIM + KAUG) / 64)   // 66 K-tiles in k_main

typedef __bf16 bf16x8 __attribute__((ext_vector_type(8)));
typedef float  f32x4  __attribute__((ext_vector_type(4)));

__device__ __forceinline__ unsigned short f2bf(float f) {
    union { float f; unsigned int u; } v;
    v.f = f;
    unsigned int u = v.u;
    return (unsigned short)((u + 0x7fffu + ((u >> 16) & 1u)) >> 16);
}

// ---------------------------------------------------------------------------
// Kernel 0: fp32 -> bf16 conversion (vectorized), used for W, A
// ---------------------------------------------------------------------------
__global__ __launch_bounds__(256) void k_cvt(
    const float4* __restrict__ in, ushort4* __restrict__ outv, int n4)
{
    int i = blockIdx.x * 256 + threadIdx.x;
    if (i < n4) {
        float4 v = in[i];
        outv[i] = make_ushort4(f2bf(v.x), f2bf(v.y), f2bf(v.z), f2bf(v.w));
    }
}

// ---------------------------------------------------------------------------
// Kernel 1: permute+convert B fp32 [E][D][R] -> Bt bf16 [D][E*R], ushort4 I/O.
// ---------------------------------------------------------------------------
__global__ __launch_bounds__(256) void k_bt(
    const float* __restrict__ B, ushort4* __restrict__ Bt4)
{
    int i4 = blockIdx.x * 256 + threadIdx.x;    // over DIM*KAUG/4 = 131072
    int idx = i4 * 4;
    int o = idx >> 7;
    int j = idx & 127;
    int e = j >> 4;
    int r = j & 15;                              // multiple of 4
    const float4 v = *(const float4*)(B + ((size_t)e * DIM + o) * RANK + r);
    Bt4[i4] = make_ushort4(f2bf(v.x), f2bf(v.y), f2bf(v.z), f2bf(v.w));
}

// ---------------------------------------------------------------------------
// Kernel 2: gate (fp32 logits + top-2 + softmax) FUSED with x fp32->bf16.
// Wave-per-token x4, no LDS, no __syncthreads.
// ---------------------------------------------------------------------------
__global__ __launch_bounds__(256) void k_gate(
    const float* __restrict__ x,
    const float* __restrict__ gW,
    float4* __restrict__ gate_out,
    ushort4* __restrict__ xb4)                 // bf16 mirror of x
{
    const int wave = threadIdx.x >> 6;
    const int lane = threadIdx.x & 63;
    const int n0 = blockIdx.x * 16 + wave * 4;  // 4 tokens per wave

    const float4* __restrict__ g4 = (const float4*)gW;   // [8][1024]
    const float4* xr0 = (const float4*)(x + (size_t)(n0 + 0) * DIM);
    const float4* xr1 = (const float4*)(x + (size_t)(n0 + 1) * DIM);
    const float4* xr2 = (const float4*)(x + (size_t)(n0 + 2) * DIM);
    const float4* xr3 = (const float4*)(x + (size_t)(n0 + 3) * DIM);
    ushort4* xw0 = xb4 + (size_t)(n0 + 0) * (DIM / 4);
    ushort4* xw1 = xb4 + (size_t)(n0 + 1) * (DIM / 4);
    ushort4* xw2 = xb4 + (size_t)(n0 + 2) * (DIM / 4);
    ushort4* xw3 = xb4 + (size_t)(n0 + 3) * (DIM / 4);

    float s[4][8];
    #pragma unroll
    for (int t = 0; t < 4; ++t)
        #pragma unroll
        for (int e = 0; e < 8; ++e) s[t][e] = 0.f;

    for (int j = 0; j < 16; ++j) {
        const int idx = j * 64 + lane;
        float4 v0 = xr0[idx];
        float4 v1 = xr1[idx];
        float4 v2 = xr2[idx];
        float4 v3 = xr3[idx];
        #pragma unroll
        for (int e = 0; e < 8; ++e) {
            const float4 g = g4[e * (DIM / 4) + idx];
            s[0][e] += v0.x * g.x + v0.y * g.y + v0.z * g.z + v0.w * g.w;
            s[1][e] += v1.x * g.x + v1.y * g.y + v1.z * g.z + v1.w * g.w;
            s[2][e] += v2.x * g.x + v2.y * g.y + v2.z * g.z + v2.w * g.w;
            s[3][e] += v3.x * g.x + v3.y * g.y + v3.z * g.z + v3.w * g.w;
        }
        xw0[idx] = make_ushort4(f2bf(v0.x), f2bf(v0.y), f2bf(v0.z), f2bf(v0.w));
        xw1[idx] = make_ushort4(f2bf(v1.x), f2bf(v1.y), f2bf(v1.z), f2bf(v1.w));
        xw2[idx] = make_ushort4(f2bf(v2.x), f2bf(v2.y), f2bf(v2.z), f2bf(v2.w));
        xw3[idx] = make_ushort4(f2bf(v3.x), f2bf(v3.y), f2bf(v3.z), f2bf(v3.w));
    }

    // butterfly: every lane ends with the full sum for all (t,e)
    #pragma unroll
    for (int t = 0; t < 4; ++t)
        #pragma unroll
        for (int e = 0; e < 8; ++e)
            #pragma unroll
            for (int off = 32; off; off >>= 1)
                s[t][e] += __shfl_xor(s[t][e], off);

    #pragma unroll
    for (int t = 0; t < 4; ++t) {
        if (lane == t) {
            int e0 = 0; float v0 = s[t][0];
            #pragma unroll
            for (int e = 1; e < 8; ++e)
                if (s[t][e] > v0) { v0 = s[t][e]; e0 = e; }
            int e1 = -1; float v1 = -INFINITY;
            #pragma unroll
            for (int e = 0; e < 8; ++e)
                if (e != e0 && s[t][e] > v1) { v1 = s[t][e]; e1 = e; }
            float b = __expf(v1 - v0);      // softmax over [v0,v1], v0 >= v1
            float w0 = 1.f / (1.f + b);
            float w1 = 1.f - w0;
            gate_out[n0 + t] = make_float4((float)e0, (float)e1, w0, w1);
        }
    }
}

// ---------------------------------------------------------------------------
// Shared GEMM machinery for k_ax: 128x128 block tile, BK=64, 4 waves (2x2),
// each wave 4x4 fragments of mfma_f32_16x16x32_bf16. global_load_lds staging.
// LDS tile: [128 rows][8 chunks of 8 bf16]; PHYSICAL chunk = logical ^ (row&7).
// ---------------------------------------------------------------------------
__device__ __forceinline__ void stage_lds(
    const unsigned short* gbase, int strideElems,
    unsigned short* ldsBase, int wave, int lane)
{
    const int l8 = lane >> 3;                    // row within 8-row chunk
    const int c8 = ((lane & 7) ^ l8) << 3;       // swizzled source column chunk
    #pragma unroll
    for (int q = 0; q < 4; ++q) {
        const int r = wave * 32 + q * 8;         // wave-uniform row base
        const unsigned short* gp = gbase + (size_t)(r + l8) * strideElems + c8;
        unsigned short* lp = ldsBase + r * 64;   // wave-uniform; HW adds lane*16B
        __builtin_amdgcn_global_load_lds(
            (const __attribute__((address_space(1))) void*)gp,
            (__attribute__((address_space(3))) void*)lp,
            16, 0, 0);
    }
}

__device__ __forceinline__ void mfma_step(
    const unsigned short* As, const unsigned short* Bs,
    int waveM, int waveN, int lane, f32x4 acc[4][4])
{
    const int quad = lane >> 4;
    const int l15  = lane & 15;
    const int x7   = l15 & 7;                    // row&7 for all fragment rows
    #pragma unroll
    for (int s = 0; s < 2; ++s) {
        const int chunk = (s << 2) | quad;       // logical k-chunk (ko>>3)
        const int po = ((chunk ^ x7) << 3);      // swizzled element offset
        bf16x8 af[4], bfv[4];
        #pragma unroll
        for (int i = 0; i < 4; ++i)
            af[i] = *(const bf16x8*)(As + (waveM * 64 + i * 16 + l15) * 64 + po);
        #pragma unroll
        for (int j = 0; j < 4; ++j)
            bfv[j] = *(const bf16x8*)(Bs + (waveN * 64 + j * 16 + l15) * 64 + po);
        #pragma unroll
        for (int i = 0; i < 4; ++i)
            #pragma unroll
            for (int j = 0; j < 4; ++j)
                acc[i][j] = __builtin_amdgcn_mfma_f32_16x16x32_bf16(
                    af[i], bfv[j], acc[i][j], 0, 0, 0);
    }
}

// ---------------------------------------------------------------------------
// Kernel 3: ax split-K GEMM. Grid (64 row-tiles, KSPLIT). Block (rb, ks)
// computes axPart[ks] rows [rb*128,+128) over K slice [ks*1024,+1024), fp32.
// ---------------------------------------------------------------------------
__global__ __launch_bounds__(256) void k_ax(
    const unsigned short* __restrict__ xb,
    const unsigned short* __restrict__ Ab,     // [128][4096] bf16
    float* __restrict__ axPart)                // [KSPLIT][8192][128] fp32
{
    __shared__ __align__(16) unsigned short As[128 * 64];
    __shared__ __align__(16) unsigned short Bs[128 * 64];
    const int tid  = threadIdx.x;
    const int wave = tid >> 6, lane = tid & 63;
    const int waveM = wave >> 1, waveN = wave & 1;
    const int rowBase = blockIdx.x * 128;
    const int ks = blockIdx.y;
    const int k0 = ks * (DIM / KSPLIT);

    f32x4 acc[4][4] = {};

    for (int it = 0; it < (DIM / KSPLIT) / 64; ++it) {
        stage_lds(xb + (size_t)rowBase * DIM + k0 + it * 64, DIM, As, wave, lane);
        stage_lds(Ab + (size_t)0 * DIM       + k0 + it * 64, DIM, Bs, wave, lane);
        __syncthreads();
        mfma_step(As, Bs, waveM, waveN, lane, acc);
        __syncthreads();
    }

    float* outp = axPart + (size_t)ks * NTOK * KAUG;
    const int quad = lane >> 4, l15 = lane & 15;
    #pragma unroll
    for (int i = 0; i < 4; ++i) {
        #pragma unroll
        for (int j = 0; j < 4; ++j) {
            const int gc = waveN * 64 + j * 16 + l15;   // 0..127
            #pragma unroll
            for (int t = 0; t < 4; ++t) {
                const int gr = rowBase + waveM * 64 + i * 16 + quad * 4 + t;
                outp[(size_t)gr * KAUG + gc] = acc[i][j][t];
            }
        }
    }
}

// ---------------------------------------------------------------------------
// Kernel 3b: sum split-K partials, apply gate weights, emit bf16 cB (ushort4)
// ---------------------------------------------------------------------------
__global__ __launch_bounds__(256) void k_scale(
    const float* __restrict__ axPart,
    const float4* __restrict__ gate_out,
    ushort4* __restrict__ cB4)
{
    int i4 = blockIdx.x * 256 + threadIdx.x;    // over NTOK*KAUG/4
    int idx = i4 * 4;
    int n = idx >> 7;
    int j = idx & 127;
    float4 s = make_float4(0.f, 0.f, 0.f, 0.f);
    #pragma unroll
    for (int ks = 0; ks < KSPLIT; ++ks) {
        const float4 v = *(const float4*)(axPart + (size_t)ks * NTOK * KAUG + idx);
        s.x += v.x; s.y += v.y; s.z += v.z; s.w += v.w;
    }
    float4 g = gate_out[n];
    int e  = j >> 4;                             // uniform across the 4 elems
    int e0 = (int)g.x;
    int e1 = (int)g.y;
    float scale = (e == e0) ? 2.f * g.z : (e == e1) ? 2.f * g.w : 0.f;
    cB4[i4] = make_ushort4(f2bf(scale * s.x), f2bf(scale * s.y),
                           f2bf(scale * s.z), f2bf(scale * s.w));
}

// ---------------------------------------------------------------------------
// Kernel 4: main GEMM, 256x256 tile, BK=64, 8-phase counted-vmcnt schedule.
// K = 4096 (xb,Wb) + 128 (cB,Bt) -> fp32 out [8192][4096]
// 16 waves (4M x 4N grid); per wave 64x64 output = 4x4 frags of 16x16.
// Phase q computes m-frag q x all 4 n-frags over full BK=64 (8 MFMA/phase).
// acc 64 VGPR + bFr 32 + aFr 8 -> ~124 regs -> 4 waves/SIMD.
// ---------------------------------------------------------------------------
__global__ __launch_bounds__(1024) void k_main(
    const unsigned short* __restrict__ xb,    // [8192][4096] bf16
    const unsigned short* __restrict__ Wb,    // [4096][4096] bf16
    const unsigned short* __restrict__ cB,    // [8192][128]  bf16
    const unsigned short* __restrict__ Bt,    // [4096][128]  bf16
    float* __restrict__ out)                  // [8192][4096] fp32
{
    __shared__ __align__(16) unsigned short sA[2][256 * 64];  // 2 x 32 KiB
    __shared__ __align__(16) unsigned short sB[2][256 * 64];  // 2 x 32 KiB

    const int tid  = threadIdx.x;
    const int wave = tid >> 6, lane = tid & 63;  // wave in [0,16)
    const int wm = wave >> 2, wn = wave & 3;     // 4 x 4 wave grid
    const int quad = lane >> 4, l15 = lane & 15;
    const int x7 = l15 & 7;                      // row&7 for frag rows

    // bijective XCD swizzle, col-major within XCD: each XCD owns 4 row-panels;
    // its 32 concurrent blocks span 4 rows x 8 cols of panels.
    const int bid  = blockIdx.x;
    const int xcd  = bid & 7, slot = bid >> 3;       // slot in [0,64)
    const int rowBase = (xcd * 4 + (slot & 3)) * 256;
    const int colBase = (slot >> 2) * 256;

    const unsigned short* aMain = xb + (size_t)rowBase * DIM;
    const unsigned short* bMain = Wb + (size_t)colBase * DIM;
    const unsigned short* aLora = cB + (size_t)rowBase * KAUG;
    const unsigned short* bLora = Bt + (size_t)colBase * KAUG;

    const int l8 = lane >> 3;
    const int c8 = ((lane & 7) ^ l8) << 3;           // swizzled global chunk

    // stage ONE half-tile (128 rows): 16 waves x 8 rows = 1 load/wave
    auto stageT = [&](int t, int half, bool isA) {
        if (t >= NKT) return;                        // uniform branch
        unsigned short* ldsR = isA ? &sA[t & 1][0] : &sB[t & 1][0];
        const unsigned short* g;
        int stride;
        if (t < DIM / 64) { g = (isA ? aMain : bMain) + t * 64;              stride = DIM;  }
        else              { g = (isA ? aLora : bLora) + (t - DIM / 64) * 64; stride = KAUG; }
        const int r0 = half * 128 + wave * 8;        // wave-uniform
        const unsigned short* gp = g + (size_t)(r0 + l8) * stride + c8;
        unsigned short* lp = ldsR + r0 * 64;
        __builtin_amdgcn_global_load_lds(
            (const __attribute__((address_space(1))) void*)gp,
            (__attribute__((address_space(3))) void*)lp,
            16, 0, 0);
    };

    f32x4 acc[4][4] = {};

    // Prologue: A(0) h0,h1; B(0) h0,h1; B(1) h0,h1  (6 loads/wave)
    // vmcnt(2): A(0)+B(0) complete, B(1) (2 loads) still in flight.
    stageT(0, 0, true);  stageT(0, 1, true);
    stageT(0, 0, false); stageT(0, 1, false);
    stageT(1, 0, false); stageT(1, 1, false);
    asm volatile("s_waitcnt vmcnt(2)" ::: "memory");
    __builtin_amdgcn_s_barrier();

    // Main loop. Safety invariants (2 barriers/phase):
    //  - A(k+1) staged q0/q1 into buf[k+1&1]: that buffer's A(k-1) reads ended
    //    at k-1 q3, barrier crossed -> safe.
    //  - B(k+2) staged q2/q3 into buf[k&1]: B(k) fully read at q0 -> safe.
    //  - vmcnt(2) at q3 leaves only B(k+2) (2 loads) in flight; everything
    //    older -- incl. A(k+1),B(k+1) -- retired before next q0 reads them.
    for (int k = 0; k < NKT; ++k) {
        const unsigned short* At = &sA[k & 1][0];
        const unsigned short* Bl = &sB[k & 1][0];
        bf16x8 bFr[4][2];                            // live across all 4 phases
        #pragma unroll
        for (int q = 0; q < 4; ++q) {
            bf16x8 aFr[2];
            #pragma unroll
            for (int ksl = 0; ksl < 2; ++ksl) {
                const int r  = wm * 64 + q * 16 + l15;
                const int ch = ksl * 4 + quad;
                aFr[ksl] = *(const bf16x8*)(At + r * 64 + ((ch ^ x7) << 3));
            }
            if (q == 0) {
                #pragma unroll
                for (int nf = 0; nf < 4; ++nf)
                    #pragma unroll
                    for (int ksl = 0; ksl < 2; ++ksl) {
                        const int r  = wn * 64 + nf * 16 + l15;
                        const int ch = ksl * 4 + quad;
                        bFr[nf][ksl] = *(const bf16x8*)(Bl + r * 64 + ((ch ^ x7) << 3));
                    }
            }
            if      (q == 0) stageT(k + 1, 0, true);
            else if (q == 1) stageT(k + 1, 1, true);
            else if (q == 2) stageT(k + 2, 0, false);
            else             stageT(k + 2, 1, false);

            __builtin_amdgcn_s_barrier();
            asm volatile("s_waitcnt lgkmcnt(0)" ::: "memory");
            __builtin_amdgcn_sched_barrier(0);       // rule #18: pin MFMAs after wait
            __builtin_amdgcn_s_setprio(1);
            #pragma unroll
            for (int nf = 0; nf < 4; ++nf)
                #pragma unroll
                for (int ksl = 0; ksl < 2; ++ksl)
                    acc[q][nf] = __builtin_amdgcn_mfma_f32_16x16x32_bf16(
                        aFr[ksl], bFr[nf][ksl], acc[q][nf], 0, 0, 0);
            __builtin_amdgcn_s_setprio(0);
            __builtin_amdgcn_sched_barrier(0);       // keep MFMA cluster in-phase
            if (q == 3) {
                if (k == NKT - 2)
                    asm volatile("s_waitcnt vmcnt(0)" ::: "memory");  // tail: A(65) must land
                else if (k < NKT - 2)
                    asm volatile("s_waitcnt vmcnt(2)" ::: "memory");  // counted, never 0
            }
            __builtin_amdgcn_s_barrier();
        }
    }

    // Epilogue: C/D mapping col=lane&15, row=quad*4+t (verified this session)
    #pragma unroll
    for (int mf = 0; mf < 4; ++mf) {
        #pragma unroll
        for (int nf = 0; nf < 4; ++nf) {
            const int gc = colBase + wn * 64 + nf * 16 + l15;
            #pragma unroll
            for (int t = 0; t < 4; ++t) {
                const int gr = rowBase + wm * 64 + mf * 16 + quad * 4 + t;
                out[(size_t)gr * DIM + gc] = acc[mf][nf][t];
            }
        }
    }
}

// ---------------------------------------------------------------------------
extern "C" void kernel_launch(void* const* d_in, const int* in_sizes, int n_in,
                              void* d_out, int out_size, void* d_ws, size_t ws_size,
                              hipStream_t stream) {
    (void)in_sizes; (void)n_in; (void)out_size; (void)ws_size;

    const float* x  = (const float*)d_in[0];  // [8192][4096]
    const float* bW = (const float*)d_in[1];  // [4096][4096]
    const float* gW = (const float*)d_in[2];  // [8][4096]
    const float* A  = (const float*)d_in[3];  // [8][16][4096] = [128][4096]
    const float* B  = (const float*)d_in[4];  // [8][4096][16]
    // d_in[5] = top_k (always 2)
    float* out = (float*)d_out;

    // workspace layout (all regions fully rewritten every launch)
    char* ws = (char*)d_ws;
    float4*         gate_out = (float4*)ws;                         //   128 KiB
    unsigned short* xb = (unsigned short*)(ws + (1u << 17));        //    64 MiB
    unsigned short* Wb = xb + (size_t)NTOK * DIM;                   //    32 MiB
    unsigned short* Ab = Wb + (size_t)DIM * DIM;                    //     1 MiB
    unsigned short* Bt = Ab + (size_t)KAUG * DIM;                   //     1 MiB
    unsigned short* cB = Bt + (size_t)DIM * KAUG;                   //     2 MiB
    float*      axPart = (float*)(cB + (size_t)NTOK * KAUG);        //    16 MiB
                                                                    // ~116 MiB

    k_gate<<<NTOK / 16, 256, 0, stream>>>(x, gW, gate_out, (ushort4*)xb);
    k_cvt <<<(DIM * DIM / 4 + 255) / 256, 256, 0, stream>>>(
        (const float4*)bW, (ushort4*)Wb, DIM * DIM / 4);
    k_cvt <<<(KAUG * DIM / 4 + 255) / 256, 256, 0, stream>>>(
        (const float4*)A, (ushort4*)Ab, KAUG * DIM / 4);
    k_bt  <<<(DIM * KAUG / 4) / 256, 256, 0, stream>>>(B, (ushort4*)Bt);
    k_ax  <<<dim3(NTOK / 128, KSPLIT), 256, 0, stream>>>(xb, Ab, axPart);
    k_scale<<<(NTOK * KAUG / 4) / 256, 256, 0, stream>>>(
        axPart, gate_out, (ushort4*)cB);
    k_main<<<dim3(512), dim3(1024), 0, stream>>>(xb, Wb, cB, Bt, out);
}

// Round 6
// 593.463 us; speedup vs baseline: 1.0092x; 1.0092x over previous
//
#include <hip/hip_runtime.h>
#include <math.h>

// ---------------------------------------------------------------------------
// Problem: N=8192 tokens, D=4096, E=8 experts, R=16, top_k=2. ALL fp32 in/out.
// out = x @ W^T + sum_{e in top2} 2*w_e * (x @ A[e]^T) @ B[e]^T
// Strategy: convert x,W,A,B to bf16 in ws; fold LoRA down-proj into the base
// GEMM as a K-extension (K = 4096 + 128), fp32 accumulate, fp32 out.
// k_main round-6: FREE-RUN schedule. 256x256 tile, BK=64, 8 waves (512 thr),
// double-buffered LDS, ONE __syncthreads per K-tile, ZERO intra-tile sync.
// Rationale (round-5 falsified the occupancy theory): MFMA floor (2163 cyc)
// and LDS-read floor (~2300 cyc) per K-step are equal-sized; 8 block-wide
// barriers/tile serialized them (sum = measured 5150 cyc, 43% MfmaUtil).
// Free-run lets waves drift inside the tile so one wave's ds_reads overlap
// another wave's MFMAs (m114 co-scheduling). Stage(k+1) issues at tile start;
// the tile-boundary __syncthreads' implicit vmcnt(0) drain lands ~free.
// LDS tiles use an XOR-8 swizzle (chunk ^= row&7) applied in GLOBAL address
// space during staging (global_load_lds LDS write pattern is fixed).
// ---------------------------------------------------------------------------

#define NTOK 8192
#define DIM  4096
#define NEXP 8
#define RANK 16
#define KAUG (NEXP * RANK)   // 128
#define KSPLIT 4             // k_ax split-K factor
#define NKT  ((DIM + KAUG) / 64)   // 66 K-tiles in k_main

typedef __bf16 bf16x8 __attribute__((ext_vector_type(8)));
typedef float  f32x4  __attribute__((ext_vector_type(4)));

__device__ __forceinline__ unsigned short f2bf(float f) {
    union { float f; unsigned int u; } v;
    v.f = f;
    unsigned int u = v.u;
    return (unsigned short)((u + 0x7fffu + ((u >> 16) & 1u)) >> 16);
}

// ---------------------------------------------------------------------------
// Kernel 0: fp32 -> bf16 conversion (vectorized), used for W, A
// ---------------------------------------------------------------------------
__global__ __launch_bounds__(256) void k_cvt(
    const float4* __restrict__ in, ushort4* __restrict__ outv, int n4)
{
    int i = blockIdx.x * 256 + threadIdx.x;
    if (i < n4) {
        float4 v = in[i];
        outv[i] = make_ushort4(f2bf(v.x), f2bf(v.y), f2bf(v.z), f2bf(v.w));
    }
}

// ---------------------------------------------------------------------------
// Kernel 1: permute+convert B fp32 [E][D][R] -> Bt bf16 [D][E*R], ushort4 I/O.
// ---------------------------------------------------------------------------
__global__ __launch_bounds__(256) void k_bt(
    const float* __restrict__ B, ushort4* __restrict__ Bt4)
{
    int i4 = blockIdx.x * 256 + threadIdx.x;    // over DIM*KAUG/4 = 131072
    int idx = i4 * 4;
    int o = idx >> 7;
    int j = idx & 127;
    int e = j >> 4;
    int r = j & 15;                              // multiple of 4
    const float4 v = *(const float4*)(B + ((size_t)e * DIM + o) * RANK + r);
    Bt4[i4] = make_ushort4(f2bf(v.x), f2bf(v.y), f2bf(v.z), f2bf(v.w));
}

// ---------------------------------------------------------------------------
// Kernel 2: gate (fp32 logits + top-2 + softmax) FUSED with x fp32->bf16.
// Wave-per-token x4, no LDS, no __syncthreads.
// ---------------------------------------------------------------------------
__global__ __launch_bounds__(256) void k_gate(
    const float* __restrict__ x,
    const float* __restrict__ gW,
    float4* __restrict__ gate_out,
    ushort4* __restrict__ xb4)                 // bf16 mirror of x
{
    const int wave = threadIdx.x >> 6;
    const int lane = threadIdx.x & 63;
    const int n0 = blockIdx.x * 16 + wave * 4;  // 4 tokens per wave

    const float4* __restrict__ g4 = (const float4*)gW;   // [8][1024]
    const float4* xr0 = (const float4*)(x + (size_t)(n0 + 0) * DIM);
    const float4* xr1 = (const float4*)(x + (size_t)(n0 + 1) * DIM);
    const float4* xr2 = (const float4*)(x + (size_t)(n0 + 2) * DIM);
    const float4* xr3 = (const float4*)(x + (size_t)(n0 + 3) * DIM);
    ushort4* xw0 = xb4 + (size_t)(n0 + 0) * (DIM / 4);
    ushort4* xw1 = xb4 + (size_t)(n0 + 1) * (DIM / 4);
    ushort4* xw2 = xb4 + (size_t)(n0 + 2) * (DIM / 4);
    ushort4* xw3 = xb4 + (size_t)(n0 + 3) * (DIM / 4);

    float s[4][8];
    #pragma unroll
    for (int t = 0; t < 4; ++t)
        #pragma unroll
        for (int e = 0; e < 8; ++e) s[t][e] = 0.f;

    for (int j = 0; j < 16; ++j) {
        const int idx = j * 64 + lane;
        float4 v0 = xr0[idx];
        float4 v1 = xr1[idx];
        float4 v2 = xr2[idx];
        float4 v3 = xr3[idx];
        #pragma unroll
        for (int e = 0; e < 8; ++e) {
            const float4 g = g4[e * (DIM / 4) + idx];
            s[0][e] += v0.x * g.x + v0.y * g.y + v0.z * g.z + v0.w * g.w;
            s[1][e] += v1.x * g.x + v1.y * g.y + v1.z * g.z + v1.w * g.w;
            s[2][e] += v2.x * g.x + v2.y * g.y + v2.z * g.z + v2.w * g.w;
            s[3][e] += v3.x * g.x + v3.y * g.y + v3.z * g.z + v3.w * g.w;
        }
        xw0[idx] = make_ushort4(f2bf(v0.x), f2bf(v0.y), f2bf(v0.z), f2bf(v0.w));
        xw1[idx] = make_ushort4(f2bf(v1.x), f2bf(v1.y), f2bf(v1.z), f2bf(v1.w));
        xw2[idx] = make_ushort4(f2bf(v2.x), f2bf(v2.y), f2bf(v2.z), f2bf(v2.w));
        xw3[idx] = make_ushort4(f2bf(v3.x), f2bf(v3.y), f2bf(v3.z), f2bf(v3.w));
    }

    // butterfly: every lane ends with the full sum for all (t,e)
    #pragma unroll
    for (int t = 0; t < 4; ++t)
        #pragma unroll
        for (int e = 0; e < 8; ++e)
            #pragma unroll
            for (int off = 32; off; off >>= 1)
                s[t][e] += __shfl_xor(s[t][e], off);

    #pragma unroll
    for (int t = 0; t < 4; ++t) {
        if (lane == t) {
            int e0 = 0; float v0 = s[t][0];
            #pragma unroll
            for (int e = 1; e < 8; ++e)
                if (s[t][e] > v0) { v0 = s[t][e]; e0 = e; }
            int e1 = -1; float v1 = -INFINITY;
            #pragma unroll
            for (int e = 0; e < 8; ++e)
                if (e != e0 && s[t][e] > v1) { v1 = s[t][e]; e1 = e; }
            float b = __expf(v1 - v0);      // softmax over [v0,v1], v0 >= v1
            float w0 = 1.f / (1.f + b);
            float w1 = 1.f - w0;
            gate_out[n0 + t] = make_float4((float)e0, (float)e1, w0, w1);
        }
    }
}

// ---------------------------------------------------------------------------
// Shared GEMM machinery for k_ax: 128x128 block tile, BK=64, 4 waves (2x2),
// each wave 4x4 fragments of mfma_f32_16x16x32_bf16. global_load_lds staging.
// LDS tile: [128 rows][8 chunks of 8 bf16]; PHYSICAL chunk = logical ^ (row&7).
// ---------------------------------------------------------------------------
__device__ __forceinline__ void stage_lds(
    const unsigned short* gbase, int strideElems,
    unsigned short* ldsBase, int wave, int lane)
{
    const int l8 = lane >> 3;                    // row within 8-row chunk
    const int c8 = ((lane & 7) ^ l8) << 3;       // swizzled source column chunk
    #pragma unroll
    for (int q = 0; q < 4; ++q) {
        const int r = wave * 32 + q * 8;         // wave-uniform row base
        const unsigned short* gp = gbase + (size_t)(r + l8) * strideElems + c8;
        unsigned short* lp = ldsBase + r * 64;   // wave-uniform; HW adds lane*16B
        __builtin_amdgcn_global_load_lds(
            (const __attribute__((address_space(1))) void*)gp,
            (__attribute__((address_space(3))) void*)lp,
            16, 0, 0);
    }
}

__device__ __forceinline__ void mfma_step(
    const unsigned short* As, const unsigned short* Bs,
    int waveM, int waveN, int lane, f32x4 acc[4][4])
{
    const int quad = lane >> 4;
    const int l15  = lane & 15;
    const int x7   = l15 & 7;                    // row&7 for all fragment rows
    #pragma unroll
    for (int s = 0; s < 2; ++s) {
        const int chunk = (s << 2) | quad;       // logical k-chunk (ko>>3)
        const int po = ((chunk ^ x7) << 3);      // swizzled element offset
        bf16x8 af[4], bfv[4];
        #pragma unroll
        for (int i = 0; i < 4; ++i)
            af[i] = *(const bf16x8*)(As + (waveM * 64 + i * 16 + l15) * 64 + po);
        #pragma unroll
        for (int j = 0; j < 4; ++j)
            bfv[j] = *(const bf16x8*)(Bs + (waveN * 64 + j * 16 + l15) * 64 + po);
        #pragma unroll
        for (int i = 0; i < 4; ++i)
            #pragma unroll
            for (int j = 0; j < 4; ++j)
                acc[i][j] = __builtin_amdgcn_mfma_f32_16x16x32_bf16(
                    af[i], bfv[j], acc[i][j], 0, 0, 0);
    }
}

// ---------------------------------------------------------------------------
// Kernel 3: ax split-K GEMM. Grid (64 row-tiles, KSPLIT). Block (rb, ks)
// computes axPart[ks] rows [rb*128,+128) over K slice [ks*1024,+1024), fp32.
// ---------------------------------------------------------------------------
__global__ __launch_bounds__(256) void k_ax(
    const unsigned short* __restrict__ xb,
    const unsigned short* __restrict__ Ab,     // [128][4096] bf16
    float* __restrict__ axPart)                // [KSPLIT][8192][128] fp32
{
    __shared__ __align__(16) unsigned short As[128 * 64];
    __shared__ __align__(16) unsigned short Bs[128 * 64];
    const int tid  = threadIdx.x;
    const int wave = tid >> 6, lane = tid & 63;
    const int waveM = wave >> 1, waveN = wave & 1;
    const int rowBase = blockIdx.x * 128;
    const int ks = blockIdx.y;
    const int k0 = ks * (DIM / KSPLIT);

    f32x4 acc[4][4] = {};

    for (int it = 0; it < (DIM / KSPLIT) / 64; ++it) {
        stage_lds(xb + (size_t)rowBase * DIM + k0 + it * 64, DIM, As, wave, lane);
        stage_lds(Ab + (size_t)0 * DIM       + k0 + it * 64, DIM, Bs, wave, lane);
        __syncthreads();
        mfma_step(As, Bs, waveM, waveN, lane, acc);
        __syncthreads();
    }

    float* outp = axPart + (size_t)ks * NTOK * KAUG;
    const int quad = lane >> 4, l15 = lane & 15;
    #pragma unroll
    for (int i = 0; i < 4; ++i) {
        #pragma unroll
        for (int j = 0; j < 4; ++j) {
            const int gc = waveN * 64 + j * 16 + l15;   // 0..127
            #pragma unroll
            for (int t = 0; t < 4; ++t) {
                const int gr = rowBase + waveM * 64 + i * 16 + quad * 4 + t;
                outp[(size_t)gr * KAUG + gc] = acc[i][j][t];
            }
        }
    }
}

// ---------------------------------------------------------------------------
// Kernel 3b: sum split-K partials, apply gate weights, emit bf16 cB (ushort4)
// ---------------------------------------------------------------------------
__global__ __launch_bounds__(256) void k_scale(
    const float* __restrict__ axPart,
    const float4* __restrict__ gate_out,
    ushort4* __restrict__ cB4)
{
    int i4 = blockIdx.x * 256 + threadIdx.x;    // over NTOK*KAUG/4
    int idx = i4 * 4;
    int n = idx >> 7;
    int j = idx & 127;
    float4 s = make_float4(0.f, 0.f, 0.f, 0.f);
    #pragma unroll
    for (int ks = 0; ks < KSPLIT; ++ks) {
        const float4 v = *(const float4*)(axPart + (size_t)ks * NTOK * KAUG + idx);
        s.x += v.x; s.y += v.y; s.z += v.z; s.w += v.w;
    }
    float4 g = gate_out[n];
    int e  = j >> 4;                             // uniform across the 4 elems
    int e0 = (int)g.x;
    int e1 = (int)g.y;
    float scale = (e == e0) ? 2.f * g.z : (e == e1) ? 2.f * g.w : 0.f;
    cB4[i4] = make_ushort4(f2bf(scale * s.x), f2bf(scale * s.y),
                           f2bf(scale * s.z), f2bf(scale * s.w));
}

// ---------------------------------------------------------------------------
// Kernel 4: main GEMM, 256x256 tile, BK=64, FREE-RUN schedule.
// K = 4096 (xb,Wb) + 128 (cB,Bt) -> fp32 out [8192][4096]
// 8 waves (2M x 4N); per wave 128x64 output = 8x4 frags of 16x16.
// Per K-tile: issue stage(k+1) [8 gload_lds] -> read 24 frags + 64 MFMA
// (compiler-scheduled, no intra-tile barriers) -> __syncthreads (its implicit
// vmcnt(0)+lgkmcnt(0) drain doubles as the staging fence; stages were issued
// a full tile body earlier so the drain is ~free). Waves drift within the
// tile so ds_read traffic overlaps other waves' MFMA pipe time.
// ---------------------------------------------------------------------------
__global__ __launch_bounds__(512) void k_main(
    const unsigned short* __restrict__ xb,    // [8192][4096] bf16
    const unsigned short* __restrict__ Wb,    // [4096][4096] bf16
    const unsigned short* __restrict__ cB,    // [8192][128]  bf16
    const unsigned short* __restrict__ Bt,    // [4096][128]  bf16
    float* __restrict__ out)                  // [8192][4096] fp32
{
    __shared__ __align__(16) unsigned short sA[2][256 * 64];  // 2 x 32 KiB
    __shared__ __align__(16) unsigned short sB[2][256 * 64];  // 2 x 32 KiB

    const int tid  = threadIdx.x;
    const int wave = tid >> 6, lane = tid & 63;  // wave in [0,8)
    const int wm = wave >> 2, wn = wave & 3;     // 2 x 4 wave grid
    const int quad = lane >> 4, l15 = lane & 15;
    const int x7 = l15 & 7;                      // row&7 for frag rows

    // bijective XCD swizzle, col-major within XCD: each XCD owns 4 row-panels;
    // its 32 concurrent blocks span 4 rows x 8 cols of panels.
    const int bid  = blockIdx.x;
    const int xcd  = bid & 7, slot = bid >> 3;       // slot in [0,64)
    const int rowBase = (xcd * 4 + (slot & 3)) * 256;
    const int colBase = (slot >> 2) * 256;

    const unsigned short* aMain = xb + (size_t)rowBase * DIM;
    const unsigned short* bMain = Wb + (size_t)colBase * DIM;
    const unsigned short* aLora = cB + (size_t)rowBase * KAUG;
    const unsigned short* bLora = Bt + (size_t)colBase * KAUG;

    const int l8 = lane >> 3;
    const int c8 = ((lane & 7) ^ l8) << 3;           // swizzled global chunk

    // stage ONE half-tile (128 rows) of A or B for K-tile t: 2 loads/wave
    auto stageT = [&](int t, int half, bool isA) {
        if (t >= NKT) return;                        // uniform branch
        unsigned short* ldsR = isA ? &sA[t & 1][0] : &sB[t & 1][0];
        const unsigned short* g;
        int stride;
        if (t < DIM / 64) { g = (isA ? aMain : bMain) + t * 64;              stride = DIM;  }
        else              { g = (isA ? aLora : bLora) + (t - DIM / 64) * 64; stride = KAUG; }
        #pragma unroll
        for (int qq = 0; qq < 2; ++qq) {
            const int r0 = half * 128 + qq * 64 + wave * 8;   // wave-uniform
            const unsigned short* gp = g + (size_t)(r0 + l8) * stride + c8;
            unsigned short* lp = ldsR + r0 * 64;
            __builtin_amdgcn_global_load_lds(
                (const __attribute__((address_space(1))) void*)gp,
                (__attribute__((address_space(3))) void*)lp,
                16, 0, 0);
        }
    };

    f32x4 acc[8][4] = {};

    // Prologue: stage tile 0 (A and B, both halves), drain, rendezvous.
    stageT(0, 0, true);  stageT(0, 1, true);
    stageT(0, 0, false); stageT(0, 1, false);
    __syncthreads();

    // Main loop: 1 barrier per K-tile. Hazard check: stage(k+1) overwrites
    // buf[(k+1)&1], whose last readers (tile k-1) completed all ds_reads
    // before the tile-k __syncthreads (reads consumed by MFMAs pre-barrier).
    // The barrier's implicit vmcnt(0) guarantees every wave's stage(k)
    // landed before any wave reads tile k.
    for (int k = 0; k < NKT; ++k) {
        const unsigned short* At = &sA[k & 1][0];
        const unsigned short* Bl = &sB[k & 1][0];

        // issue next tile's staging first: full tile body hides the latency
        stageT(k + 1, 0, true);  stageT(k + 1, 1, true);
        stageT(k + 1, 0, false); stageT(k + 1, 1, false);

        // fragment reads + MFMAs, no barriers: compiler schedules, waves drift
        bf16x8 bFr[4][2];
        #pragma unroll
        for (int nf = 0; nf < 4; ++nf)
            #pragma unroll
            for (int ksl = 0; ksl < 2; ++ksl) {
                const int r  = wn * 64 + nf * 16 + l15;
                const int ch = ksl * 4 + quad;
                bFr[nf][ksl] = *(const bf16x8*)(Bl + r * 64 + ((ch ^ x7) << 3));
            }
        #pragma unroll
        for (int q = 0; q < 4; ++q) {
            bf16x8 aFr[2][2];
            #pragma unroll
            for (int mi = 0; mi < 2; ++mi)
                #pragma unroll
                for (int ksl = 0; ksl < 2; ++ksl) {
                    const int r  = wm * 128 + (q * 2 + mi) * 16 + l15;
                    const int ch = ksl * 4 + quad;
                    aFr[mi][ksl] = *(const bf16x8*)(At + r * 64 + ((ch ^ x7) << 3));
                }
            #pragma unroll
            for (int mi = 0; mi < 2; ++mi)
                #pragma unroll
                for (int nf = 0; nf < 4; ++nf)
                    #pragma unroll
                    for (int ksl = 0; ksl < 2; ++ksl)
                        acc[q * 2 + mi][nf] = __builtin_amdgcn_mfma_f32_16x16x32_bf16(
                            aFr[mi][ksl], bFr[nf][ksl], acc[q * 2 + mi][nf], 0, 0, 0);
        }

        __syncthreads();   // implicit vmcnt(0)+lgkmcnt(0): staging fence
    }

    // Epilogue: same C/D mapping as verified 128^2 kernel
    #pragma unroll
    for (int mf = 0; mf < 8; ++mf) {
        #pragma unroll
        for (int nf = 0; nf < 4; ++nf) {
            const int gc = colBase + wn * 64 + nf * 16 + l15;
            #pragma unroll
            for (int t = 0; t < 4; ++t) {
                const int gr = rowBase + wm * 128 + mf * 16 + quad * 4 + t;
                out[(size_t)gr * DIM + gc] = acc[mf][nf][t];
            }
        }
    }
}

// ---------------------------------------------------------------------------
extern "C" void kernel_launch(void* const* d_in, const int* in_sizes, int n_in,
                              void* d_out, int out_size, void* d_ws, size_t ws_size,
                              hipStream_t stream) {
    (void)in_sizes; (void)n_in; (void)out_size; (void)ws_size;

    const float* x  = (const float*)d_in[0];  // [8192][4096]
    const float* bW = (const float*)d_in[1];  // [4096][4096]
    const float* gW = (const float*)d_in[2];  // [8][4096]
    const float* A  = (const float*)d_in[3];  // [8][16][4096] = [128][4096]
    const float* B  = (const float*)d_in[4];  // [8][4096][16]
    // d_in[5] = top_k (always 2)
    float* out = (float*)d_out;

    // workspace layout (all regions fully rewritten every launch)
    char* ws = (char*)d_ws;
    float4*         gate_out = (float4*)ws;                         //   128 KiB
    unsigned short* xb = (unsigned short*)(ws + (1u << 17));        //    64 MiB
    unsigned short* Wb = xb + (size_t)NTOK * DIM;                   //    32 MiB
    unsigned short* Ab = Wb + (size_t)DIM * DIM;                    //     1 MiB
    unsigned short* Bt = Ab + (size_t)KAUG * DIM;                   //     1 MiB
    unsigned short* cB = Bt + (size_t)DIM * KAUG;                   //     2 MiB
    float*      axPart = (float*)(cB + (size_t)NTOK * KAUG);        //    16 MiB
                                                                    // ~116 MiB

    k_gate<<<NTOK / 16, 256, 0, stream>>>(x, gW, gate_out, (ushort4*)xb);
    k_cvt <<<(DIM * DIM / 4 + 255) / 256, 256, 0, stream>>>(
        (const float4*)bW, (ushort4*)Wb, DIM * DIM / 4);
    k_cvt <<<(KAUG * DIM / 4 + 255) / 256, 256, 0, stream>>>(
        (const float4*)A, (ushort4*)Ab, KAUG * DIM / 4);
    k_bt  <<<(DIM * KAUG / 4) / 256, 256, 0, stream>>>(B, (ushort4*)Bt);
    k_ax  <<<dim3(NTOK / 128, KSPLIT), 256, 0, stream>>>(xb, Ab, axPart);
    k_scale<<<(NTOK * KAUG / 4) / 256, 256, 0, stream>>>(
        axPart, gate_out, (ushort4*)cB);
    k_main<<<dim3(512), dim3(512), 0, stream>>>(xb, Wb, cB, Bt, out);
}

// Round 7
// 589.705 us; speedup vs baseline: 1.0156x; 1.0064x over previous
//
#include <hip/hip_runtime.h>
#include <math.h>

// ---------------------------------------------------------------------------
// Problem: N=8192 tokens, D=4096, E=8 experts, R=16, top_k=2. ALL fp32 in/out.
// out = x @ W^T + sum_{e in top2} 2*w_e * (x @ A[e]^T) @ B[e]^T
// Strategy: convert x,W,A,B to bf16 in ws; fold LoRA down-proj into the base
// GEMM as a K-extension (K = 4096 + 128), fp32 accumulate, fp32 out.
// k_main round-7: free-run shell (1 __syncthreads per K-tile) + SOFTWARE-
// PIPELINED fragment reads with counted lgkmcnt. Evidence: 2-phase, 8-phase,
// and free-run all measured tile time = MFMA floor (~2480cy) + LDS-port floor
// (~2800cy) SERIALIZED (MfmaUtil 43% in all three). The compiler issues each
// ds_read lazily just before its consuming MFMA, so the LDS port and matrix
// pipe never overlap. Fix: 8 static phases of 8 MFMA; phase p issues phase
// p+1's reads, then waits a COUNTED lgkmcnt (retires only the prior phase's
// reads), sched_barrier(0)-fenced so the scheduler can't re-cluster.
// Steady-state port load/phase (16 reads x 12cy = 192cy) hides under the
// 310cy MFMA window. Per-acc MFMA order unchanged -> bit-identical output.
// LDS tiles use an XOR-8 swizzle (chunk ^= row&7) applied in GLOBAL address
// space during staging (global_load_lds LDS write pattern is fixed).
// ---------------------------------------------------------------------------

#define NTOK 8192
#define DIM  4096
#define NEXP 8
#define RANK 16
#define KAUG (NEXP * RANK)   // 128
#define KSPLIT 4             // k_ax split-K factor
#define NKT  ((DIM + KAUG) / 64)   // 66 K-tiles in k_main

typedef __bf16 bf16x8 __attribute__((ext_vector_type(8)));
typedef float  f32x4  __attribute__((ext_vector_type(4)));

__device__ __forceinline__ unsigned short f2bf(float f) {
    union { float f; unsigned int u; } v;
    v.f = f;
    unsigned int u = v.u;
    return (unsigned short)((u + 0x7fffu + ((u >> 16) & 1u)) >> 16);
}

// ---------------------------------------------------------------------------
// Kernel 0: fp32 -> bf16 conversion (vectorized), used for W, A
// ---------------------------------------------------------------------------
__global__ __launch_bounds__(256) void k_cvt(
    const float4* __restrict__ in, ushort4* __restrict__ outv, int n4)
{
    int i = blockIdx.x * 256 + threadIdx.x;
    if (i < n4) {
        float4 v = in[i];
        outv[i] = make_ushort4(f2bf(v.x), f2bf(v.y), f2bf(v.z), f2bf(v.w));
    }
}

// ---------------------------------------------------------------------------
// Kernel 1: permute+convert B fp32 [E][D][R] -> Bt bf16 [D][E*R], ushort4 I/O.
// ---------------------------------------------------------------------------
__global__ __launch_bounds__(256) void k_bt(
    const float* __restrict__ B, ushort4* __restrict__ Bt4)
{
    int i4 = blockIdx.x * 256 + threadIdx.x;    // over DIM*KAUG/4 = 131072
    int idx = i4 * 4;
    int o = idx >> 7;
    int j = idx & 127;
    int e = j >> 4;
    int r = j & 15;                              // multiple of 4
    const float4 v = *(const float4*)(B + ((size_t)e * DIM + o) * RANK + r);
    Bt4[i4] = make_ushort4(f2bf(v.x), f2bf(v.y), f2bf(v.z), f2bf(v.w));
}

// ---------------------------------------------------------------------------
// Kernel 2: gate (fp32 logits + top-2 + softmax) FUSED with x fp32->bf16.
// Wave-per-token x4, no LDS, no __syncthreads.
// ---------------------------------------------------------------------------
__global__ __launch_bounds__(256) void k_gate(
    const float* __restrict__ x,
    const float* __restrict__ gW,
    float4* __restrict__ gate_out,
    ushort4* __restrict__ xb4)                 // bf16 mirror of x
{
    const int wave = threadIdx.x >> 6;
    const int lane = threadIdx.x & 63;
    const int n0 = blockIdx.x * 16 + wave * 4;  // 4 tokens per wave

    const float4* __restrict__ g4 = (const float4*)gW;   // [8][1024]
    const float4* xr0 = (const float4*)(x + (size_t)(n0 + 0) * DIM);
    const float4* xr1 = (const float4*)(x + (size_t)(n0 + 1) * DIM);
    const float4* xr2 = (const float4*)(x + (size_t)(n0 + 2) * DIM);
    const float4* xr3 = (const float4*)(x + (size_t)(n0 + 3) * DIM);
    ushort4* xw0 = xb4 + (size_t)(n0 + 0) * (DIM / 4);
    ushort4* xw1 = xb4 + (size_t)(n0 + 1) * (DIM / 4);
    ushort4* xw2 = xb4 + (size_t)(n0 + 2) * (DIM / 4);
    ushort4* xw3 = xb4 + (size_t)(n0 + 3) * (DIM / 4);

    float s[4][8];
    #pragma unroll
    for (int t = 0; t < 4; ++t)
        #pragma unroll
        for (int e = 0; e < 8; ++e) s[t][e] = 0.f;

    for (int j = 0; j < 16; ++j) {
        const int idx = j * 64 + lane;
        float4 v0 = xr0[idx];
        float4 v1 = xr1[idx];
        float4 v2 = xr2[idx];
        float4 v3 = xr3[idx];
        #pragma unroll
        for (int e = 0; e < 8; ++e) {
            const float4 g = g4[e * (DIM / 4) + idx];
            s[0][e] += v0.x * g.x + v0.y * g.y + v0.z * g.z + v0.w * g.w;
            s[1][e] += v1.x * g.x + v1.y * g.y + v1.z * g.z + v1.w * g.w;
            s[2][e] += v2.x * g.x + v2.y * g.y + v2.z * g.z + v2.w * g.w;
            s[3][e] += v3.x * g.x + v3.y * g.y + v3.z * g.z + v3.w * g.w;
        }
        xw0[idx] = make_ushort4(f2bf(v0.x), f2bf(v0.y), f2bf(v0.z), f2bf(v0.w));
        xw1[idx] = make_ushort4(f2bf(v1.x), f2bf(v1.y), f2bf(v1.z), f2bf(v1.w));
        xw2[idx] = make_ushort4(f2bf(v2.x), f2bf(v2.y), f2bf(v2.z), f2bf(v2.w));
        xw3[idx] = make_ushort4(f2bf(v3.x), f2bf(v3.y), f2bf(v3.z), f2bf(v3.w));
    }

    // butterfly: every lane ends with the full sum for all (t,e)
    #pragma unroll
    for (int t = 0; t < 4; ++t)
        #pragma unroll
        for (int e = 0; e < 8; ++e)
            #pragma unroll
            for (int off = 32; off; off >>= 1)
                s[t][e] += __shfl_xor(s[t][e], off);

    #pragma unroll
    for (int t = 0; t < 4; ++t) {
        if (lane == t) {
            int e0 = 0; float v0 = s[t][0];
            #pragma unroll
            for (int e = 1; e < 8; ++e)
                if (s[t][e] > v0) { v0 = s[t][e]; e0 = e; }
            int e1 = -1; float v1 = -INFINITY;
            #pragma unroll
            for (int e = 0; e < 8; ++e)
                if (e != e0 && s[t][e] > v1) { v1 = s[t][e]; e1 = e; }
            float b = __expf(v1 - v0);      // softmax over [v0,v1], v0 >= v1
            float w0 = 1.f / (1.f + b);
            float w1 = 1.f - w0;
            gate_out[n0 + t] = make_float4((float)e0, (float)e1, w0, w1);
        }
    }
}

// ---------------------------------------------------------------------------
// Shared GEMM machinery for k_ax: 128x128 block tile, BK=64, 4 waves (2x2),
// each wave 4x4 fragments of mfma_f32_16x16x32_bf16. global_load_lds staging.
// LDS tile: [128 rows][8 chunks of 8 bf16]; PHYSICAL chunk = logical ^ (row&7).
// ---------------------------------------------------------------------------
__device__ __forceinline__ void stage_lds(
    const unsigned short* gbase, int strideElems,
    unsigned short* ldsBase, int wave, int lane)
{
    const int l8 = lane >> 3;                    // row within 8-row chunk
    const int c8 = ((lane & 7) ^ l8) << 3;       // swizzled source column chunk
    #pragma unroll
    for (int q = 0; q < 4; ++q) {
        const int r = wave * 32 + q * 8;         // wave-uniform row base
        const unsigned short* gp = gbase + (size_t)(r + l8) * strideElems + c8;
        unsigned short* lp = ldsBase + r * 64;   // wave-uniform; HW adds lane*16B
        __builtin_amdgcn_global_load_lds(
            (const __attribute__((address_space(1))) void*)gp,
            (__attribute__((address_space(3))) void*)lp,
            16, 0, 0);
    }
}

__device__ __forceinline__ void mfma_step(
    const unsigned short* As, const unsigned short* Bs,
    int waveM, int waveN, int lane, f32x4 acc[4][4])
{
    const int quad = lane >> 4;
    const int l15  = lane & 15;
    const int x7   = l15 & 7;                    // row&7 for all fragment rows
    #pragma unroll
    for (int s = 0; s < 2; ++s) {
        const int chunk = (s << 2) | quad;       // logical k-chunk (ko>>3)
        const int po = ((chunk ^ x7) << 3);      // swizzled element offset
        bf16x8 af[4], bfv[4];
        #pragma unroll
        for (int i = 0; i < 4; ++i)
            af[i] = *(const bf16x8*)(As + (waveM * 64 + i * 16 + l15) * 64 + po);
        #pragma unroll
        for (int j = 0; j < 4; ++j)
            bfv[j] = *(const bf16x8*)(Bs + (waveN * 64 + j * 16 + l15) * 64 + po);
        #pragma unroll
        for (int i = 0; i < 4; ++i)
            #pragma unroll
            for (int j = 0; j < 4; ++j)
                acc[i][j] = __builtin_amdgcn_mfma_f32_16x16x32_bf16(
                    af[i], bfv[j], acc[i][j], 0, 0, 0);
    }
}

// ---------------------------------------------------------------------------
// Kernel 3: ax split-K GEMM. Grid (64 row-tiles, KSPLIT). Block (rb, ks)
// computes axPart[ks] rows [rb*128,+128) over K slice [ks*1024,+1024), fp32.
// ---------------------------------------------------------------------------
__global__ __launch_bounds__(256) void k_ax(
    const unsigned short* __restrict__ xb,
    const unsigned short* __restrict__ Ab,     // [128][4096] bf16
    float* __restrict__ axPart)                // [KSPLIT][8192][128] fp32
{
    __shared__ __align__(16) unsigned short As[128 * 64];
    __shared__ __align__(16) unsigned short Bs[128 * 64];
    const int tid  = threadIdx.x;
    const int wave = tid >> 6, lane = tid & 63;
    const int waveM = wave >> 1, waveN = wave & 1;
    const int rowBase = blockIdx.x * 128;
    const int ks = blockIdx.y;
    const int k0 = ks * (DIM / KSPLIT);

    f32x4 acc[4][4] = {};

    for (int it = 0; it < (DIM / KSPLIT) / 64; ++it) {
        stage_lds(xb + (size_t)rowBase * DIM + k0 + it * 64, DIM, As, wave, lane);
        stage_lds(Ab + (size_t)0 * DIM       + k0 + it * 64, DIM, Bs, wave, lane);
        __syncthreads();
        mfma_step(As, Bs, waveM, waveN, lane, acc);
        __syncthreads();
    }

    float* outp = axPart + (size_t)ks * NTOK * KAUG;
    const int quad = lane >> 4, l15 = lane & 15;
    #pragma unroll
    for (int i = 0; i < 4; ++i) {
        #pragma unroll
        for (int j = 0; j < 4; ++j) {
            const int gc = waveN * 64 + j * 16 + l15;   // 0..127
            #pragma unroll
            for (int t = 0; t < 4; ++t) {
                const int gr = rowBase + waveM * 64 + i * 16 + quad * 4 + t;
                outp[(size_t)gr * KAUG + gc] = acc[i][j][t];
            }
        }
    }
}

// ---------------------------------------------------------------------------
// Kernel 3b: sum split-K partials, apply gate weights, emit bf16 cB (ushort4)
// ---------------------------------------------------------------------------
__global__ __launch_bounds__(256) void k_scale(
    const float* __restrict__ axPart,
    const float4* __restrict__ gate_out,
    ushort4* __restrict__ cB4)
{
    int i4 = blockIdx.x * 256 + threadIdx.x;    // over NTOK*KAUG/4
    int idx = i4 * 4;
    int n = idx >> 7;
    int j = idx & 127;
    float4 s = make_float4(0.f, 0.f, 0.f, 0.f);
    #pragma unroll
    for (int ks = 0; ks < KSPLIT; ++ks) {
        const float4 v = *(const float4*)(axPart + (size_t)ks * NTOK * KAUG + idx);
        s.x += v.x; s.y += v.y; s.z += v.z; s.w += v.w;
    }
    float4 g = gate_out[n];
    int e  = j >> 4;                             // uniform across the 4 elems
    int e0 = (int)g.x;
    int e1 = (int)g.y;
    float scale = (e == e0) ? 2.f * g.z : (e == e1) ? 2.f * g.w : 0.f;
    cB4[i4] = make_ushort4(f2bf(scale * s.x), f2bf(scale * s.y),
                           f2bf(scale * s.z), f2bf(scale * s.w));
}

// ---------------------------------------------------------------------------
// Kernel 4: main GEMM, 256x256 tile, BK=64, free-run + pipelined-lgkm.
// K = 4096 (xb,Wb) + 128 (cB,Bt) -> fp32 out [8192][4096]
// 8 waves (2M x 4N); per wave 128x64 output = 8x4 frags of 16x16.
// Per K-tile: stage(k+1) -> 8 static phases {issue next reads, counted
// lgkmcnt, sched_barrier, 8 MFMA} -> __syncthreads. Phase p = (q=p>>1,
// ks=p&1): MFMAs use A-frags (q,ks) read in phase p-1 and B-frags[ks] read
// up-front/p0. Steady state: 2 reads in flight during every MFMA cluster.
// ---------------------------------------------------------------------------
__global__ __launch_bounds__(512) void k_main(
    const unsigned short* __restrict__ xb,    // [8192][4096] bf16
    const unsigned short* __restrict__ Wb,    // [4096][4096] bf16
    const unsigned short* __restrict__ cB,    // [8192][128]  bf16
    const unsigned short* __restrict__ Bt,    // [4096][128]  bf16
    float* __restrict__ out)                  // [8192][4096] fp32
{
    __shared__ __align__(16) unsigned short sA[2][256 * 64];  // 2 x 32 KiB
    __shared__ __align__(16) unsigned short sB[2][256 * 64];  // 2 x 32 KiB

    const int tid  = threadIdx.x;
    const int wave = tid >> 6, lane = tid & 63;  // wave in [0,8)
    const int wm = wave >> 2, wn = wave & 3;     // 2 x 4 wave grid
    const int quad = lane >> 4, l15 = lane & 15;
    const int x7 = l15 & 7;                      // row&7 for frag rows

    // bijective XCD swizzle, col-major within XCD: each XCD owns 4 row-panels;
    // its 32 concurrent blocks span 4 rows x 8 cols of panels.
    const int bid  = blockIdx.x;
    const int xcd  = bid & 7, slot = bid >> 3;       // slot in [0,64)
    const int rowBase = (xcd * 4 + (slot & 3)) * 256;
    const int colBase = (slot >> 2) * 256;

    const unsigned short* aMain = xb + (size_t)rowBase * DIM;
    const unsigned short* bMain = Wb + (size_t)colBase * DIM;
    const unsigned short* aLora = cB + (size_t)rowBase * KAUG;
    const unsigned short* bLora = Bt + (size_t)colBase * KAUG;

    const int l8 = lane >> 3;
    const int c8 = ((lane & 7) ^ l8) << 3;           // swizzled global chunk

    // stage ONE half-tile (128 rows) of A or B for K-tile t: 2 loads/wave
    auto stageT = [&](int t, int half, bool isA) {
        if (t >= NKT) return;                        // uniform branch
        unsigned short* ldsR = isA ? &sA[t & 1][0] : &sB[t & 1][0];
        const unsigned short* g;
        int stride;
        if (t < DIM / 64) { g = (isA ? aMain : bMain) + t * 64;              stride = DIM;  }
        else              { g = (isA ? aLora : bLora) + (t - DIM / 64) * 64; stride = KAUG; }
        #pragma unroll
        for (int qq = 0; qq < 2; ++qq) {
            const int r0 = half * 128 + qq * 64 + wave * 8;   // wave-uniform
            const unsigned short* gp = g + (size_t)(r0 + l8) * stride + c8;
            unsigned short* lp = ldsR + r0 * 64;
            __builtin_amdgcn_global_load_lds(
                (const __attribute__((address_space(1))) void*)gp,
                (__attribute__((address_space(3))) void*)lp,
                16, 0, 0);
        }
    };

    // fragment-read address helpers (swizzled)
    auto aAddr = [&](const unsigned short* At, int mfrag, int ks) {
        const int r  = wm * 128 + mfrag * 16 + l15;
        const int ch = ks * 4 + quad;
        return (const bf16x8*)(At + r * 64 + ((ch ^ x7) << 3));
    };
    auto bAddr = [&](const unsigned short* Bl, int nf, int ks) {
        const int r  = wn * 64 + nf * 16 + l15;
        const int ch = ks * 4 + quad;
        return (const bf16x8*)(Bl + r * 64 + ((ch ^ x7) << 3));
    };

    f32x4 acc[8][4] = {};

    // Prologue: stage tile 0 (A and B, both halves), drain, rendezvous.
    stageT(0, 0, true);  stageT(0, 1, true);
    stageT(0, 0, false); stageT(0, 1, false);
    __syncthreads();

    for (int k = 0; k < NKT; ++k) {
        const unsigned short* At = &sA[k & 1][0];
        const unsigned short* Bl = &sB[k & 1][0];

        // issue next tile's staging first: full tile body hides the latency
        stageT(k + 1, 0, true);  stageT(k + 1, 1, true);
        stageT(k + 1, 0, false); stageT(k + 1, 1, false);

        // ---- software-pipelined fragment reads, counted lgkmcnt ----
        // lgkm ledger (per wave): pre-loop 6 reads (B[ks0] x4 + A(0,ks0) x2).
        // p0 issues 6 (B[ks1] x4 + A(0,ks1) x2), waits lgkm(6).
        // p1..p6 issue 2 (A(q+1) frags), wait lgkm(2). p7 waits lgkm(0).
        bf16x8 bFr[2][4];                            // [ks][nf], live all tile
        bf16x8 aF[2][2];                             // [p&1][mi], ping-pong
        #pragma unroll
        for (int nf = 0; nf < 4; ++nf) bFr[0][nf] = *bAddr(Bl, nf, 0);
        aF[0][0] = *aAddr(At, 0, 0);
        aF[0][1] = *aAddr(At, 1, 0);

        #pragma unroll
        for (int p = 0; p < 8; ++p) {
            const int q  = p >> 1;                   // compile-time in unroll
            const int ks = p & 1;
            // issue NEXT phase's reads (phase p+1 = (q', ks'))
            if (p == 0) {
                #pragma unroll
                for (int nf = 0; nf < 4; ++nf) bFr[1][nf] = *bAddr(Bl, nf, 1);
                aF[1][0] = *aAddr(At, 0, 1);
                aF[1][1] = *aAddr(At, 1, 1);
            } else if (p < 7) {
                const int qn  = (p + 1) >> 1;
                const int ksn = (p + 1) & 1;
                aF[(p + 1) & 1][0] = *aAddr(At, qn * 2 + 0, ksn);
                aF[(p + 1) & 1][1] = *aAddr(At, qn * 2 + 1, ksn);
            }
            // counted wait: retire prior phase's reads, keep just-issued in flight
            if (p == 0)      asm volatile("s_waitcnt lgkmcnt(6)" ::: "memory");
            else if (p < 7)  asm volatile("s_waitcnt lgkmcnt(2)" ::: "memory");
            else             asm volatile("s_waitcnt lgkmcnt(0)" ::: "memory");
            __builtin_amdgcn_sched_barrier(0);       // rule #18: pin MFMAs below
            __builtin_amdgcn_s_setprio(1);
            #pragma unroll
            for (int mi = 0; mi < 2; ++mi)
                #pragma unroll
                for (int nf = 0; nf < 4; ++nf)
                    acc[q * 2 + mi][nf] = __builtin_amdgcn_mfma_f32_16x16x32_bf16(
                        aF[p & 1][mi], bFr[ks][nf], acc[q * 2 + mi][nf], 0, 0, 0);
            __builtin_amdgcn_s_setprio(0);
            __builtin_amdgcn_sched_barrier(0);       // keep clusters in order
        }

        __syncthreads();   // implicit vmcnt(0)+lgkmcnt(0): staging fence
    }

    // Epilogue: same C/D mapping as verified 128^2 kernel
    #pragma unroll
    for (int mf = 0; mf < 8; ++mf) {
        #pragma unroll
        for (int nf = 0; nf < 4; ++nf) {
            const int gc = colBase + wn * 64 + nf * 16 + l15;
            #pragma unroll
            for (int t = 0; t < 4; ++t) {
                const int gr = rowBase + wm * 128 + mf * 16 + quad * 4 + t;
                out[(size_t)gr * DIM + gc] = acc[mf][nf][t];
            }
        }
    }
}

// ---------------------------------------------------------------------------
extern "C" void kernel_launch(void* const* d_in, const int* in_sizes, int n_in,
                              void* d_out, int out_size, void* d_ws, size_t ws_size,
                              hipStream_t stream) {
    (void)in_sizes; (void)n_in; (void)out_size; (void)ws_size;

    const float* x  = (const float*)d_in[0];  // [8192][4096]
    const float* bW = (const float*)d_in[1];  // [4096][4096]
    const float* gW = (const float*)d_in[2];  // [8][4096]
    const float* A  = (const float*)d_in[3];  // [8][16][4096] = [128][4096]
    const float* B  = (const float*)d_in[4];  // [8][4096][16]
    // d_in[5] = top_k (always 2)
    float* out = (float*)d_out;

    // workspace layout (all regions fully rewritten every launch)
    char* ws = (char*)d_ws;
    float4*         gate_out = (float4*)ws;                         //   128 KiB
    unsigned short* xb = (unsigned short*)(ws + (1u << 17));        //    64 MiB
    unsigned short* Wb = xb + (size_t)NTOK * DIM;                   //    32 MiB
    unsigned short* Ab = Wb + (size_t)DIM * DIM;                    //     1 MiB
    unsigned short* Bt = Ab + (size_t)KAUG * DIM;                   //     1 MiB
    unsigned short* cB = Bt + (size_t)DIM * KAUG;                   //     2 MiB
    float*      axPart = (float*)(cB + (size_t)NTOK * KAUG);        //    16 MiB
                                                                    // ~116 MiB

    k_gate<<<NTOK / 16, 256, 0, stream>>>(x, gW, gate_out, (ushort4*)xb);
    k_cvt <<<(DIM * DIM / 4 + 255) / 256, 256, 0, stream>>>(
        (const float4*)bW, (ushort4*)Wb, DIM * DIM / 4);
    k_cvt <<<(KAUG * DIM / 4 + 255) / 256, 256, 0, stream>>>(
        (const float4*)A, (ushort4*)Ab, KAUG * DIM / 4);
    k_bt  <<<(DIM * KAUG / 4) / 256, 256, 0, stream>>>(B, (ushort4*)Bt);
    k_ax  <<<dim3(NTOK / 128, KSPLIT), 256, 0, stream>>>(xb, Ab, axPart);
    k_scale<<<(NTOK * KAUG / 4) / 256, 256, 0, stream>>>(
        axPart, gate_out, (ushort4*)cB);
    k_main<<<dim3(512), dim3(512), 0, stream>>>(xb, Wb, cB, Bt, out);
}